// Round 1
// baseline (242.804 us; speedup 1.0000x reference)
//
#include <hip/hip_runtime.h>
#include <math.h>

#define NROI 2000
#define NCLS 21
#define NFG  20
#define NPAD 2048

// ---- workspace layout (bytes) ----
#define OFF_BOXES   0u          // float4 [NFG*NROI]            640000
#define OFF_PROBS   640000u     // float  [NFG*NROI]            160000
#define OFF_SIDX    800000u     // int    [NFG*NPAD]            163840
#define OFF_SBOX    963840u     // float4 [NFG*NPAD]            655360
#define OFF_VC      1619200u    // int    [NFG] (padded)           128
#define OFF_KEEP    1619328u    // int    [NFG*NROI]            160000
#define OFF_MASK    1779328u    // u64    [NFG*NPAD*32]       10485760
// total ~12.27 MB

// -------- kernel 1: softmax + box decode + clip; zero keep flags --------
__global__ void k_decode(const float* __restrict__ rois,
                         const float* __restrict__ locs,
                         const float* __restrict__ scores,
                         const float* __restrict__ scale,
                         float4* __restrict__ boxes,
                         float* __restrict__ probs,
                         int* __restrict__ keepw) {
#pragma clang fp contract(off)
    int n = blockIdx.x * blockDim.x + threadIdx.x;
    if (n >= NROI) return;

#pragma unroll
    for (int c = 0; c < NFG; ++c) keepw[c * NROI + n] = 0;

    float s[NCLS];
    float m = -__builtin_inff();
#pragma unroll
    for (int k = 0; k < NCLS; ++k) {
        s[k] = scores[n * NCLS + k];
        m = fmaxf(m, s[k]);
    }
    float sum = 0.0f;
#pragma unroll
    for (int k = 0; k < NCLS; ++k) {
        s[k] = expf(s[k] - m);
        sum += s[k];
    }

    float y1 = rois[n * 4 + 0], x1 = rois[n * 4 + 1];
    float y2 = rois[n * 4 + 2], x2 = rois[n * 4 + 3];
    float h = y2 - y1, w = x2 - x1;
    float cy = y1 + 0.5f * h, cx = x1 + 0.5f * w;
    float sc = scale[0];
    float oh = 600.0f / sc, ow = 800.0f / sc;

#pragma unroll
    for (int c = 1; c < NCLS; ++c) {
        float dy = locs[n * (NCLS * 4) + c * 4 + 0] * 0.1f;
        float dx = locs[n * (NCLS * 4) + c * 4 + 1] * 0.1f;
        float dh = locs[n * (NCLS * 4) + c * 4 + 2] * 0.2f;
        float dw = locs[n * (NCLS * 4) + c * 4 + 3] * 0.2f;
        float ncy = dy * h + cy;
        float ncx = dx * w + cx;
        float nh = expf(dh) * h;
        float nw = expf(dw) * w;
        float b0 = ncy - 0.5f * nh;
        float b1 = ncx - 0.5f * nw;
        float b2 = ncy + 0.5f * nh;
        float b3 = ncx + 0.5f * nw;
        b0 = fminf(fmaxf(b0, 0.0f), oh);
        b1 = fminf(fmaxf(b1, 0.0f), ow);
        b2 = fminf(fmaxf(b2, 0.0f), oh);
        b3 = fminf(fmaxf(b3, 0.0f), ow);
        int o = (c - 1) * NROI + n;
        boxes[o] = make_float4(b0, b1, b2, b3);
        probs[o] = s[c] / sum;
    }
}

// -------- kernel 2: per-class bitonic sort of packed (key,idx) --------
__global__ void __launch_bounds__(1024) k_sort(const float* __restrict__ probs,
                                               const float4* __restrict__ boxes,
                                               int* __restrict__ sidx,
                                               float4* __restrict__ sbox,
                                               int* __restrict__ Vc) {
    int c = blockIdx.x;
    int t = threadIdx.x;
    __shared__ unsigned long long a[NPAD];
    __shared__ int vcount;
    if (t == 0) vcount = 0;

    for (int e = t; e < NPAD; e += 1024) {
        unsigned int u;
        if (e < NROI) {
            float pr = probs[c * NROI + e];
            float key = (pr > 0.05f) ? pr : -__builtin_inff();
            u = __float_as_uint(key);
        } else {
            u = __float_as_uint(-__builtin_inff());
        }
        u ^= (u >> 31) ? 0xFFFFFFFFu : 0x80000000u;     // order-preserving map
        a[e] = ((unsigned long long)(~u) << 32) | (unsigned int)e; // asc == desc-by-prob, ties idx asc
    }
    __syncthreads();

    for (int k = 2; k <= NPAD; k <<= 1) {
        for (int j = k >> 1; j > 0; j >>= 1) {
            for (int e = t; e < NPAD; e += 1024) {
                int ixj = e ^ j;
                if (ixj > e) {
                    unsigned long long x = a[e], y = a[ixj];
                    bool up = ((e & k) == 0);
                    bool sw = up ? (x > y) : (x < y);
                    if (sw) { a[e] = y; a[ixj] = x; }
                }
            }
            __syncthreads();
        }
    }

    int cnt = 0;
    for (int e = t; e < NPAD; e += 1024) {
        unsigned long long p = a[e];
        unsigned int hi = (unsigned int)(p >> 32);
        bool valid = hi < 0x80000000u;   // key was a positive float (prob > 0.05)
        cnt += valid ? 1 : 0;
        int orig = (int)(p & 0xFFFFFFFFu);
        sidx[c * NPAD + e] = orig;
        float4 b = (orig < NROI) ? boxes[c * NROI + orig] : make_float4(0, 0, 0, 0);
        sbox[c * NPAD + e] = b;
    }
    if (cnt) atomicAdd(&vcount, cnt);
    __syncthreads();
    if (t == 0) Vc[c] = vcount;
}

// -------- kernel 3: suppression bitmask (upper triangle, rows < V) --------
__global__ void k_mask(const float4* __restrict__ sbox,
                       const int* __restrict__ Vc,
                       unsigned long long* __restrict__ mask) {
#pragma clang fp contract(off)
    int c = blockIdx.y;
    int V = Vc[c];
    int r = blockIdx.x * 8 + (threadIdx.x >> 5);
    if (r >= V) return;
    int jb = threadIdx.x & 31;
    const float4* sb = sbox + c * NPAD;
    float4 rb = sb[r];
    float areaR = (rb.z - rb.x) * (rb.w - rb.y);
    unsigned long long bits = 0;
    int j0 = jb << 6;
    for (int j2 = 0; j2 < 64; ++j2) {
        int j = j0 + j2;
        if (j > r) {
            float4 cb = sb[j];
            float ty = fmaxf(rb.x, cb.x);
            float tx = fmaxf(rb.y, cb.y);
            float by = fminf(rb.z, cb.z);
            float bx = fminf(rb.w, cb.w);
            float ih = fmaxf(by - ty, 0.0f);
            float iw = fmaxf(bx - tx, 0.0f);
            float inter = ih * iw;
            float areaC = (cb.z - cb.x) * (cb.w - cb.y);
            float denom = ((areaR + areaC) - inter) + 1e-12f;
            float iou = inter / denom;
            if (iou > 0.3f) bits |= (1ULL << j2);
        }
    }
    mask[((size_t)(c * NPAD) + r) * 32 + jb] = bits;
}

// -------- kernel 4: sequential greedy scan, 1 wave per class --------
#define PF 16
__global__ void __launch_bounds__(64) k_scan(const int* __restrict__ sidx,
                                             const int* __restrict__ Vc,
                                             const unsigned long long* __restrict__ mask,
                                             int* __restrict__ keepw) {
    int c = blockIdx.x;
    int V = Vc[c];
    int lane = threadIdx.x;
    int l = lane & 31;
    const unsigned long long* mrow = mask + (size_t)c * NPAD * 32;
    const int* si = sidx + c * NPAD;

    unsigned long long remv = 0;
    unsigned long long pf[PF];
#pragma unroll
    for (int k = 0; k < PF; ++k)
        pf[k] = (k < V) ? mrow[(size_t)k * 32 + l] : 0ULL;

    for (int base = 0; base < V; base += PF) {
#pragma unroll
        for (int k = 0; k < PF; ++k) {
            int i = base + k;
            if (i < V) {
                unsigned long long row = pf[k];
                int nx = i + PF;
                pf[k] = (nx < V) ? mrow[(size_t)nx * 32 + l] : 0ULL;
                unsigned long long wsup = __shfl(remv, i >> 6);
                bool keep = ((wsup >> (i & 63)) & 1ULL) == 0ULL;
                int orig = si[i];
                if (lane == 0) keepw[c * NROI + orig] = keep ? 1 : 0;
                if (keep) remv |= row;
            }
        }
    }
}

// -------- kernel 5: final outputs --------
__global__ void k_out(const float4* __restrict__ boxes,
                      const float* __restrict__ probs,
                      const int* __restrict__ keepw,
                      float* __restrict__ out) {
    int t = blockIdx.x * blockDim.x + threadIdx.x;
    if (t >= NFG * NROI) return;
    int c = t / NROI;
    int k = keepw[t];
    float4 b = boxes[t];
    float p = probs[t];
    float* o5 = out + (size_t)t * 5;
    if (k) {
        o5[0] = b.x; o5[1] = b.y; o5[2] = b.z; o5[3] = b.w; o5[4] = p;
    } else {
        o5[0] = 0.0f; o5[1] = 0.0f; o5[2] = 0.0f; o5[3] = 0.0f; o5[4] = 0.0f;
    }
    out[NFG * NROI * 5 + t] = k ? 1.0f : 0.0f;          // keep mask (bool -> 0/1)
    out[NFG * NROI * 6 + t] = (float)c;                 // labels
}

extern "C" void kernel_launch(void* const* d_in, const int* in_sizes, int n_in,
                              void* d_out, int out_size, void* d_ws, size_t ws_size,
                              hipStream_t stream) {
    const float* rois   = (const float*)d_in[0];
    const float* locs   = (const float*)d_in[1];
    const float* scores = (const float*)d_in[2];
    const float* scale  = (const float*)d_in[3];
    float* out = (float*)d_out;

    char* ws = (char*)d_ws;
    float4* boxes = (float4*)(ws + OFF_BOXES);
    float*  probs = (float*)(ws + OFF_PROBS);
    int*    sidx  = (int*)(ws + OFF_SIDX);
    float4* sbox  = (float4*)(ws + OFF_SBOX);
    int*    Vc    = (int*)(ws + OFF_VC);
    int*    keepw = (int*)(ws + OFF_KEEP);
    unsigned long long* mask = (unsigned long long*)(ws + OFF_MASK);

    hipLaunchKernelGGL(k_decode, dim3((NROI + 255) / 256), dim3(256), 0, stream,
                       rois, locs, scores, scale, boxes, probs, keepw);
    hipLaunchKernelGGL(k_sort, dim3(NFG), dim3(1024), 0, stream,
                       probs, boxes, sidx, sbox, Vc);
    hipLaunchKernelGGL(k_mask, dim3(NPAD / 8, NFG), dim3(256), 0, stream,
                       sbox, Vc, mask);
    hipLaunchKernelGGL(k_scan, dim3(NFG), dim3(64), 0, stream,
                       sidx, Vc, mask, keepw);
    hipLaunchKernelGGL(k_out, dim3((NFG * NROI + 255) / 256), dim3(256), 0, stream,
                       boxes, probs, keepw, out);
}

// Round 2
// 160.869 us; speedup vs baseline: 1.5093x; 1.5093x over previous
//
#include <hip/hip_runtime.h>
#include <math.h>

#define NROI 2000
#define NCLS 21
#define NFG  20
#define NPAD 2048

// ---- workspace layout (bytes) ----
#define OFF_BOXES   0u          // float4 [NFG*NROI]            640000
#define OFF_PROBS   640000u     // float  [NFG*NROI]            160000
#define OFF_SIDX    800000u     // int    [NFG*NPAD]            163840
#define OFF_SBOX    963840u     // float4 [NFG*NPAD]            655360
#define OFF_VC      1619200u    // int    [NFG] (padded)           128
#define OFF_KEEP    1619328u    // int    [NFG*NROI]            160000
#define OFF_MASK    1779328u    // u64    [NFG*NPAD*32]       10485760
// total ~12.27 MB

// -------- kernel 1: softmax + box decode + clip; zero keep flags --------
__global__ void k_decode(const float* __restrict__ rois,
                         const float* __restrict__ locs,
                         const float* __restrict__ scores,
                         const float* __restrict__ scale,
                         float4* __restrict__ boxes,
                         float* __restrict__ probs,
                         int* __restrict__ keepw) {
#pragma clang fp contract(off)
    int n = blockIdx.x * blockDim.x + threadIdx.x;
    if (n >= NROI) return;

#pragma unroll
    for (int c = 0; c < NFG; ++c) keepw[c * NROI + n] = 0;

    float s[NCLS];
    float m = -__builtin_inff();
#pragma unroll
    for (int k = 0; k < NCLS; ++k) {
        s[k] = scores[n * NCLS + k];
        m = fmaxf(m, s[k]);
    }
    float sum = 0.0f;
#pragma unroll
    for (int k = 0; k < NCLS; ++k) {
        s[k] = expf(s[k] - m);
        sum += s[k];
    }

    float y1 = rois[n * 4 + 0], x1 = rois[n * 4 + 1];
    float y2 = rois[n * 4 + 2], x2 = rois[n * 4 + 3];
    float h = y2 - y1, w = x2 - x1;
    float cy = y1 + 0.5f * h, cx = x1 + 0.5f * w;
    float sc = scale[0];
    float oh = 600.0f / sc, ow = 800.0f / sc;

#pragma unroll
    for (int c = 1; c < NCLS; ++c) {
        float dy = locs[n * (NCLS * 4) + c * 4 + 0] * 0.1f;
        float dx = locs[n * (NCLS * 4) + c * 4 + 1] * 0.1f;
        float dh = locs[n * (NCLS * 4) + c * 4 + 2] * 0.2f;
        float dw = locs[n * (NCLS * 4) + c * 4 + 3] * 0.2f;
        float ncy = dy * h + cy;
        float ncx = dx * w + cx;
        float nh = expf(dh) * h;
        float nw = expf(dw) * w;
        float b0 = ncy - 0.5f * nh;
        float b1 = ncx - 0.5f * nw;
        float b2 = ncy + 0.5f * nh;
        float b3 = ncx + 0.5f * nw;
        b0 = fminf(fmaxf(b0, 0.0f), oh);
        b1 = fminf(fmaxf(b1, 0.0f), ow);
        b2 = fminf(fmaxf(b2, 0.0f), oh);
        b3 = fminf(fmaxf(b3, 0.0f), ow);
        int o = (c - 1) * NROI + n;
        boxes[o] = make_float4(b0, b1, b2, b3);
        probs[o] = s[c] / sum;
    }
}

// -------- kernel 2: per-class bitonic sort of packed (key,idx) --------
__global__ void __launch_bounds__(1024) k_sort(const float* __restrict__ probs,
                                               const float4* __restrict__ boxes,
                                               int* __restrict__ sidx,
                                               float4* __restrict__ sbox,
                                               int* __restrict__ Vc) {
    int c = blockIdx.x;
    int t = threadIdx.x;
    __shared__ unsigned long long a[NPAD];
    __shared__ int vcount;
    if (t == 0) vcount = 0;

    for (int e = t; e < NPAD; e += 1024) {
        unsigned int u;
        if (e < NROI) {
            float pr = probs[c * NROI + e];
            float key = (pr > 0.05f) ? pr : -__builtin_inff();
            u = __float_as_uint(key);
        } else {
            u = __float_as_uint(-__builtin_inff());
        }
        u ^= (u >> 31) ? 0xFFFFFFFFu : 0x80000000u;     // order-preserving map
        a[e] = ((unsigned long long)(~u) << 32) | (unsigned int)e; // asc == desc-by-prob, ties idx asc
    }
    __syncthreads();

    for (int k = 2; k <= NPAD; k <<= 1) {
        for (int j = k >> 1; j > 0; j >>= 1) {
            for (int e = t; e < NPAD; e += 1024) {
                int ixj = e ^ j;
                if (ixj > e) {
                    unsigned long long x = a[e], y = a[ixj];
                    bool up = ((e & k) == 0);
                    bool sw = up ? (x > y) : (x < y);
                    if (sw) { a[e] = y; a[ixj] = x; }
                }
            }
            __syncthreads();
        }
    }

    int cnt = 0;
    for (int e = t; e < NPAD; e += 1024) {
        unsigned long long p = a[e];
        unsigned int hi = (unsigned int)(p >> 32);
        bool valid = hi < 0x80000000u;   // key was a positive float (prob > 0.05)
        cnt += valid ? 1 : 0;
        int orig = (int)(p & 0xFFFFFFFFu);
        sidx[c * NPAD + e] = orig;
        float4 b = (orig < NROI) ? boxes[c * NROI + orig] : make_float4(0, 0, 0, 0);
        sbox[c * NPAD + e] = b;
    }
    if (cnt) atomicAdd(&vcount, cnt);
    __syncthreads();
    if (t == 0) Vc[c] = vcount;
}

// -------- kernel 3: suppression bitmask (upper triangle, rows < V) --------
__global__ void k_mask(const float4* __restrict__ sbox,
                       const int* __restrict__ Vc,
                       unsigned long long* __restrict__ mask) {
#pragma clang fp contract(off)
    int c = blockIdx.y;
    int V = Vc[c];
    int r = blockIdx.x * 8 + (threadIdx.x >> 5);
    if (r >= V) return;
    int jb = threadIdx.x & 31;
    const float4* sb = sbox + c * NPAD;
    float4 rb = sb[r];
    float areaR = (rb.z - rb.x) * (rb.w - rb.y);
    unsigned long long bits = 0;
    int j0 = jb << 6;
    for (int j2 = 0; j2 < 64; ++j2) {
        int j = j0 + j2;
        if (j > r) {
            float4 cb = sb[j];
            float ty = fmaxf(rb.x, cb.x);
            float tx = fmaxf(rb.y, cb.y);
            float by = fminf(rb.z, cb.z);
            float bx = fminf(rb.w, cb.w);
            float ih = fmaxf(by - ty, 0.0f);
            float iw = fmaxf(bx - tx, 0.0f);
            float inter = ih * iw;
            float areaC = (cb.z - cb.x) * (cb.w - cb.y);
            float denom = ((areaR + areaC) - inter) + 1e-12f;
            float iou = inter / denom;
            if (iou > 0.3f) bits |= (1ULL << j2);
        }
    }
    mask[((size_t)(c * NPAD) + r) * 32 + jb] = bits;
}

// -------- kernel 4: tiled greedy scan, 1 wave per class --------
// Lane l<32 owns suppression word l (columns 64l..64l+63); lanes 32..63 mirror.
// Per 64-row tile: in-register resolution over a uniform alive bitmask with
// ffs jumps (iterations = #kept in tile), kept rows' mask rows OR'd lane-
// parallel into remv. Diagonal block prefetched one tile ahead.
__global__ void __launch_bounds__(64) k_scan(const int* __restrict__ sidx,
                                             const int* __restrict__ Vc,
                                             const unsigned long long* __restrict__ mask,
                                             int* __restrict__ keepw) {
    int c = blockIdx.x;
    int V = Vc[c];
    if (V <= 0) return;
    int lane = threadIdx.x;
    int w = lane & 31;
    const unsigned long long* mbase = mask + (size_t)c * NPAD * 32;
    const int* si = sidx + c * NPAD;

    int ntiles = (V + 63) >> 6;
    unsigned long long remv = 0;
    // prefetch diagonal block of tile 0: lane i -> mask[row i][word 0]
    unsigned long long d = mbase[(size_t)lane * 32 + 0];

    for (int t = 0; t < ntiles; ++t) {
        unsigned long long dn = 0;
        if (t + 1 < ntiles)
            dn = mbase[(size_t)(64 * (t + 1) + lane) * 32 + (t + 1)];

        unsigned long long rv = __shfl(remv, t);            // word t, uniform
        int rem = V - 64 * t;
        unsigned long long validm = (rem >= 64) ? ~0ULL : ((1ULL << rem) - 1ULL);
        unsigned long long cur = (~rv) & validm;            // alive going in
        unsigned long long kept = 0;
        unsigned long long acc = 0;

        while (cur) {
            int j = __ffsll((unsigned long long)cur) - 1;   // next unsuppressed -> kept
            kept |= 1ULL << j;
            unsigned long long wj = __shfl(d, j);           // its diag suppression word
            cur &= ~wj;
            cur &= ~(1ULL << j);
            acc |= mbase[(size_t)(64 * t + j) * 32 + w];    // full row, lane-parallel
        }
        remv |= acc;

        int r = 64 * t + lane;
        if (r < V) {
            int orig = si[r];
            keepw[c * NROI + orig] = (int)((kept >> lane) & 1ULL);
        }
        d = dn;
    }
}

// -------- kernel 5: final outputs --------
__global__ void k_out(const float4* __restrict__ boxes,
                      const float* __restrict__ probs,
                      const int* __restrict__ keepw,
                      float* __restrict__ out) {
    int t = blockIdx.x * blockDim.x + threadIdx.x;
    if (t >= NFG * NROI) return;
    int c = t / NROI;
    int k = keepw[t];
    float4 b = boxes[t];
    float p = probs[t];
    float* o5 = out + (size_t)t * 5;
    if (k) {
        o5[0] = b.x; o5[1] = b.y; o5[2] = b.z; o5[3] = b.w; o5[4] = p;
    } else {
        o5[0] = 0.0f; o5[1] = 0.0f; o5[2] = 0.0f; o5[3] = 0.0f; o5[4] = 0.0f;
    }
    out[NFG * NROI * 5 + t] = k ? 1.0f : 0.0f;          // keep mask (bool -> 0/1)
    out[NFG * NROI * 6 + t] = (float)c;                 // labels
}

extern "C" void kernel_launch(void* const* d_in, const int* in_sizes, int n_in,
                              void* d_out, int out_size, void* d_ws, size_t ws_size,
                              hipStream_t stream) {
    const float* rois   = (const float*)d_in[0];
    const float* locs   = (const float*)d_in[1];
    const float* scores = (const float*)d_in[2];
    const float* scale  = (const float*)d_in[3];
    float* out = (float*)d_out;

    char* ws = (char*)d_ws;
    float4* boxes = (float4*)(ws + OFF_BOXES);
    float*  probs = (float*)(ws + OFF_PROBS);
    int*    sidx  = (int*)(ws + OFF_SIDX);
    float4* sbox  = (float4*)(ws + OFF_SBOX);
    int*    Vc    = (int*)(ws + OFF_VC);
    int*    keepw = (int*)(ws + OFF_KEEP);
    unsigned long long* mask = (unsigned long long*)(ws + OFF_MASK);

    hipLaunchKernelGGL(k_decode, dim3((NROI + 255) / 256), dim3(256), 0, stream,
                       rois, locs, scores, scale, boxes, probs, keepw);
    hipLaunchKernelGGL(k_sort, dim3(NFG), dim3(1024), 0, stream,
                       probs, boxes, sidx, sbox, Vc);
    hipLaunchKernelGGL(k_mask, dim3(NPAD / 8, NFG), dim3(256), 0, stream,
                       sbox, Vc, mask);
    hipLaunchKernelGGL(k_scan, dim3(NFG), dim3(64), 0, stream,
                       sidx, Vc, mask, keepw);
    hipLaunchKernelGGL(k_out, dim3((NFG * NROI + 255) / 256), dim3(256), 0, stream,
                       boxes, probs, keepw, out);
}

// Round 3
// 109.455 us; speedup vs baseline: 2.2183x; 1.4697x over previous
//
#include <hip/hip_runtime.h>
#include <math.h>

#define NROI 2000
#define NCLS 21
#define NFG  20
#define NPAD 2048

// ---- workspace layout (bytes) ----
#define OFF_BOXES   0u          // float4 [NFG*NROI]            640000
#define OFF_PROBS   640000u     // float  [NFG*NROI]            160000
#define OFF_SIDX    800000u     // int    [NFG*NPAD]            163840
#define OFF_SBOX    963840u     // float4 [NFG*NPAD]            655360
#define OFF_VC      1619200u    // int    [NFG] (padded)           128
#define OFF_KEEP    1619328u    // int    [NFG*NROI]            160000
#define OFF_MASK    1779328u    // u64    [NFG*NPAD*32]       10485760
// total ~12.27 MB

// -------- kernel 1: softmax + box decode + clip; zero keep flags --------
__global__ void k_decode(const float* __restrict__ rois,
                         const float* __restrict__ locs,
                         const float* __restrict__ scores,
                         const float* __restrict__ scale,
                         float4* __restrict__ boxes,
                         float* __restrict__ probs,
                         int* __restrict__ keepw) {
#pragma clang fp contract(off)
    int n = blockIdx.x * blockDim.x + threadIdx.x;
    if (n >= NROI) return;

#pragma unroll
    for (int c = 0; c < NFG; ++c) keepw[c * NROI + n] = 0;

    float s[NCLS];
    float m = -__builtin_inff();
#pragma unroll
    for (int k = 0; k < NCLS; ++k) {
        s[k] = scores[n * NCLS + k];
        m = fmaxf(m, s[k]);
    }
    float sum = 0.0f;
#pragma unroll
    for (int k = 0; k < NCLS; ++k) {
        s[k] = expf(s[k] - m);
        sum += s[k];
    }

    float y1 = rois[n * 4 + 0], x1 = rois[n * 4 + 1];
    float y2 = rois[n * 4 + 2], x2 = rois[n * 4 + 3];
    float h = y2 - y1, w = x2 - x1;
    float cy = y1 + 0.5f * h, cx = x1 + 0.5f * w;
    float sc = scale[0];
    float oh = 600.0f / sc, ow = 800.0f / sc;

#pragma unroll
    for (int c = 1; c < NCLS; ++c) {
        float dy = locs[n * (NCLS * 4) + c * 4 + 0] * 0.1f;
        float dx = locs[n * (NCLS * 4) + c * 4 + 1] * 0.1f;
        float dh = locs[n * (NCLS * 4) + c * 4 + 2] * 0.2f;
        float dw = locs[n * (NCLS * 4) + c * 4 + 3] * 0.2f;
        float ncy = dy * h + cy;
        float ncx = dx * w + cx;
        float nh = expf(dh) * h;
        float nw = expf(dw) * w;
        float b0 = ncy - 0.5f * nh;
        float b1 = ncx - 0.5f * nw;
        float b2 = ncy + 0.5f * nh;
        float b3 = ncx + 0.5f * nw;
        b0 = fminf(fmaxf(b0, 0.0f), oh);
        b1 = fminf(fmaxf(b1, 0.0f), ow);
        b2 = fminf(fmaxf(b2, 0.0f), oh);
        b3 = fminf(fmaxf(b3, 0.0f), ow);
        int o = (c - 1) * NROI + n;
        boxes[o] = make_float4(b0, b1, b2, b3);
        probs[o] = s[c] / sum;
    }
}

// -------- kernel 2: per-class bitonic sort of packed (key,idx) --------
__global__ void __launch_bounds__(1024) k_sort(const float* __restrict__ probs,
                                               const float4* __restrict__ boxes,
                                               int* __restrict__ sidx,
                                               float4* __restrict__ sbox,
                                               int* __restrict__ Vc) {
    int c = blockIdx.x;
    int t = threadIdx.x;
    __shared__ unsigned long long a[NPAD];
    __shared__ int vcount;
    if (t == 0) vcount = 0;

    for (int e = t; e < NPAD; e += 1024) {
        unsigned int u;
        if (e < NROI) {
            float pr = probs[c * NROI + e];
            float key = (pr > 0.05f) ? pr : -__builtin_inff();
            u = __float_as_uint(key);
        } else {
            u = __float_as_uint(-__builtin_inff());
        }
        u ^= (u >> 31) ? 0xFFFFFFFFu : 0x80000000u;     // order-preserving map
        a[e] = ((unsigned long long)(~u) << 32) | (unsigned int)e; // asc == desc-by-prob, ties idx asc
    }
    __syncthreads();

    for (int k = 2; k <= NPAD; k <<= 1) {
        for (int j = k >> 1; j > 0; j >>= 1) {
            for (int e = t; e < NPAD; e += 1024) {
                int ixj = e ^ j;
                if (ixj > e) {
                    unsigned long long x = a[e], y = a[ixj];
                    bool up = ((e & k) == 0);
                    bool sw = up ? (x > y) : (x < y);
                    if (sw) { a[e] = y; a[ixj] = x; }
                }
            }
            __syncthreads();
        }
    }

    int cnt = 0;
    for (int e = t; e < NPAD; e += 1024) {
        unsigned long long p = a[e];
        unsigned int hi = (unsigned int)(p >> 32);
        bool valid = hi < 0x80000000u;   // key was a positive float (prob > 0.05)
        cnt += valid ? 1 : 0;
        int orig = (int)(p & 0xFFFFFFFFu);
        sidx[c * NPAD + e] = orig;
        float4 b = (orig < NROI) ? boxes[c * NROI + orig] : make_float4(0, 0, 0, 0);
        sbox[c * NPAD + e] = b;
    }
    if (cnt) atomicAdd(&vcount, cnt);
    __syncthreads();
    if (t == 0) Vc[c] = vcount;
}

// -------- kernel 3: suppression bitmask --------
// Only words that k_scan can consume-after-write are computed:
//   word jb == row's tile (diagonal block, feeds the d/shfl path), or
//   jb > row's tile with columns < V (feeds future remv reads).
// Lower-triangle / beyond-V words are left unwritten; k_scan provably
// masks them (validm / consumed-before-written).
__global__ void k_mask(const float4* __restrict__ sbox,
                       const int* __restrict__ Vc,
                       unsigned long long* __restrict__ mask) {
#pragma clang fp contract(off)
    int c = blockIdx.y;
    int V = Vc[c];
    int r = blockIdx.x * 8 + (threadIdx.x >> 5);
    if (r >= V) return;
    int jb = threadIdx.x & 31;
    int tr = r >> 6;
    if (jb < tr) return;                    // consumed before written
    int j0 = jb << 6;
    if (jb > tr && j0 >= V) return;         // columns never consulted
    const float4* sb = sbox + c * NPAD;
    float4 rb = sb[r];
    float areaR = (rb.z - rb.x) * (rb.w - rb.y);
    unsigned long long bits = 0;
    for (int j2 = 0; j2 < 64; ++j2) {
        int j = j0 + j2;
        if (j > r) {
            float4 cb = sb[j];
            float ty = fmaxf(rb.x, cb.x);
            float tx = fmaxf(rb.y, cb.y);
            float by = fminf(rb.z, cb.z);
            float bx = fminf(rb.w, cb.w);
            float ih = fmaxf(by - ty, 0.0f);
            float iw = fmaxf(bx - tx, 0.0f);
            float inter = ih * iw;
            float areaC = (cb.z - cb.x) * (cb.w - cb.y);
            float denom = ((areaR + areaC) - inter) + 1e-12f;
            float iou = inter / denom;
            if (iou > 0.3f) bits |= (1ULL << j2);
        }
    }
    mask[((size_t)(c * NPAD) + r) * 32 + jb] = bits;
}

// -------- kernel 4: tiled greedy scan, 1 wave per class --------
// Per 64-row tile:
//   1. issue next tile's diagonal-block load (1 u64/lane)
//   2. issue ALL 64 row-words of this tile unconditionally (pf[64], one
//      vmcnt batch — loads don't depend on the kept decision)
//   3. register-only ffs/shfl resolution over the diagonal -> kept bitmask
//      (this hides the pf latency)
//   4. branchless masked OR of pf into distributed remv
__global__ void __launch_bounds__(64, 1) k_scan(const int* __restrict__ sidx,
                                                const int* __restrict__ Vc,
                                                const unsigned long long* __restrict__ mask,
                                                int* __restrict__ keepw) {
    int c = blockIdx.x;
    int V = Vc[c];
    if (V <= 0) return;
    int lane = threadIdx.x;
    int w = lane & 31;
    const unsigned long long* mbase = mask + (size_t)c * NPAD * 32;
    const int* si = sidx + c * NPAD;

    int ntiles = (V + 63) >> 6;
    unsigned long long remv = 0;
    unsigned long long d = mbase[(size_t)lane * 32 + 0];   // diag block, tile 0

    for (int t = 0; t < ntiles; ++t) {
        unsigned long long dn = 0;
        if (t + 1 < ntiles)
            dn = mbase[(size_t)(64 * (t + 1) + lane) * 32 + (t + 1)];

        // unconditional row-word loads for this tile (independent, batched)
        unsigned long long pf[64];
        const unsigned long long* rp = mbase + (size_t)(64 * t) * 32 + w;
#pragma unroll
        for (int j = 0; j < 64; ++j) pf[j] = rp[(size_t)j * 32];

        // register-only greedy resolution on the diagonal block
        unsigned long long rv = __shfl(remv, t);            // word t, uniform
        int rem = V - 64 * t;
        unsigned long long validm = (rem >= 64) ? ~0ULL : ((1ULL << rem) - 1ULL);
        unsigned long long cur = (~rv) & validm;
        unsigned long long kept = 0;
        while (cur) {
            int j = __ffsll((unsigned long long)cur) - 1;
            kept |= 1ULL << j;
            cur &= ~__shfl(d, j);
            cur &= ~(1ULL << j);
        }

        // branchless masked accumulate (garbage words are provably masked)
        unsigned long long acc = 0;
#pragma unroll
        for (int j = 0; j < 64; ++j) {
            unsigned long long sel = 0ULL - ((kept >> j) & 1ULL);
            acc |= pf[j] & sel;
        }
        remv |= acc;

        int r = 64 * t + lane;
        if (r < V) keepw[c * NROI + si[r]] = (int)((kept >> lane) & 1ULL);
        d = dn;
    }
}

// -------- kernel 5: final outputs --------
__global__ void k_out(const float4* __restrict__ boxes,
                      const float* __restrict__ probs,
                      const int* __restrict__ keepw,
                      float* __restrict__ out) {
    int t = blockIdx.x * blockDim.x + threadIdx.x;
    if (t >= NFG * NROI) return;
    int c = t / NROI;
    int k = keepw[t];
    float4 b = boxes[t];
    float p = probs[t];
    float* o5 = out + (size_t)t * 5;
    if (k) {
        o5[0] = b.x; o5[1] = b.y; o5[2] = b.z; o5[3] = b.w; o5[4] = p;
    } else {
        o5[0] = 0.0f; o5[1] = 0.0f; o5[2] = 0.0f; o5[3] = 0.0f; o5[4] = 0.0f;
    }
    out[NFG * NROI * 5 + t] = k ? 1.0f : 0.0f;          // keep mask (bool -> 0/1)
    out[NFG * NROI * 6 + t] = (float)c;                 // labels
}

extern "C" void kernel_launch(void* const* d_in, const int* in_sizes, int n_in,
                              void* d_out, int out_size, void* d_ws, size_t ws_size,
                              hipStream_t stream) {
    const float* rois   = (const float*)d_in[0];
    const float* locs   = (const float*)d_in[1];
    const float* scores = (const float*)d_in[2];
    const float* scale  = (const float*)d_in[3];
    float* out = (float*)d_out;

    char* ws = (char*)d_ws;
    float4* boxes = (float4*)(ws + OFF_BOXES);
    float*  probs = (float*)(ws + OFF_PROBS);
    int*    sidx  = (int*)(ws + OFF_SIDX);
    float4* sbox  = (float4*)(ws + OFF_SBOX);
    int*    Vc    = (int*)(ws + OFF_VC);
    int*    keepw = (int*)(ws + OFF_KEEP);
    unsigned long long* mask = (unsigned long long*)(ws + OFF_MASK);

    hipLaunchKernelGGL(k_decode, dim3((NROI + 255) / 256), dim3(256), 0, stream,
                       rois, locs, scores, scale, boxes, probs, keepw);
    hipLaunchKernelGGL(k_sort, dim3(NFG), dim3(1024), 0, stream,
                       probs, boxes, sidx, sbox, Vc);
    hipLaunchKernelGGL(k_mask, dim3(NPAD / 8, NFG), dim3(256), 0, stream,
                       sbox, Vc, mask);
    hipLaunchKernelGGL(k_scan, dim3(NFG), dim3(64), 0, stream,
                       sidx, Vc, mask, keepw);
    hipLaunchKernelGGL(k_out, dim3((NFG * NROI + 255) / 256), dim3(256), 0, stream,
                       boxes, probs, keepw, out);
}

// Round 4
// 104.101 us; speedup vs baseline: 2.3324x; 1.0514x over previous
//
#include <hip/hip_runtime.h>
#include <math.h>

#define NROI 2000
#define NCLS 21
#define NFG  20
#define NPAD 2048

// ---- workspace layout (bytes) ----
#define OFF_BOXES   0u          // float4 [NFG*NROI]            640000
#define OFF_PROBS   640000u     // float  [NFG*NROI]            160000
#define OFF_SIDX    800000u     // int    [NFG*NPAD]            163840
#define OFF_SBOX    963840u     // float4 [NFG*NPAD]            655360
#define OFF_VC      1619200u    // int    [NFG] (padded)           128
#define OFF_KEEP    1619328u    // int    [NFG*NROI]            160000
#define OFF_MASK    1779328u    // u64    [NFG*NPAD*32]       10485760
// total ~12.27 MB

typedef unsigned long long u64;

// -------- kernel 1: softmax + box decode + clip; zero keep flags --------
__global__ void k_decode(const float* __restrict__ rois,
                         const float* __restrict__ locs,
                         const float* __restrict__ scores,
                         const float* __restrict__ scale,
                         float4* __restrict__ boxes,
                         float* __restrict__ probs,
                         int* __restrict__ keepw) {
#pragma clang fp contract(off)
    int n = blockIdx.x * blockDim.x + threadIdx.x;
    if (n >= NROI) return;

#pragma unroll
    for (int c = 0; c < NFG; ++c) keepw[c * NROI + n] = 0;

    float s[NCLS];
    float m = -__builtin_inff();
#pragma unroll
    for (int k = 0; k < NCLS; ++k) {
        s[k] = scores[n * NCLS + k];
        m = fmaxf(m, s[k]);
    }
    float sum = 0.0f;
#pragma unroll
    for (int k = 0; k < NCLS; ++k) {
        s[k] = expf(s[k] - m);
        sum += s[k];
    }

    float y1 = rois[n * 4 + 0], x1 = rois[n * 4 + 1];
    float y2 = rois[n * 4 + 2], x2 = rois[n * 4 + 3];
    float h = y2 - y1, w = x2 - x1;
    float cy = y1 + 0.5f * h, cx = x1 + 0.5f * w;
    float sc = scale[0];
    float oh = 600.0f / sc, ow = 800.0f / sc;

#pragma unroll
    for (int c = 1; c < NCLS; ++c) {
        float dy = locs[n * (NCLS * 4) + c * 4 + 0] * 0.1f;
        float dx = locs[n * (NCLS * 4) + c * 4 + 1] * 0.1f;
        float dh = locs[n * (NCLS * 4) + c * 4 + 2] * 0.2f;
        float dw = locs[n * (NCLS * 4) + c * 4 + 3] * 0.2f;
        float ncy = dy * h + cy;
        float ncx = dx * w + cx;
        float nh = expf(dh) * h;
        float nw = expf(dw) * w;
        float b0 = ncy - 0.5f * nh;
        float b1 = ncx - 0.5f * nw;
        float b2 = ncy + 0.5f * nh;
        float b3 = ncx + 0.5f * nw;
        b0 = fminf(fmaxf(b0, 0.0f), oh);
        b1 = fminf(fmaxf(b1, 0.0f), ow);
        b2 = fminf(fmaxf(b2, 0.0f), oh);
        b3 = fminf(fmaxf(b3, 0.0f), ow);
        int o = (c - 1) * NROI + n;
        boxes[o] = make_float4(b0, b1, b2, b3);
        probs[o] = s[c] / sum;
    }
}

// -------- kernel 2: register-resident bitonic sort (256 thr x 8 elems) ----
// j in {1,2,4}: in-thread (static reg indices); j in {8..256}: shfl_xor
// (laneMask = j>>3, wave-local); j in {512,1024}: LDS (3 phases total).
#define CSW(A,B,UP) { u64 lo_ = x[A] < x[B] ? x[A] : x[B]; \
                      u64 hi_ = x[A] < x[B] ? x[B] : x[A]; \
                      x[A] = (UP) ? lo_ : hi_; x[B] = (UP) ? hi_ : lo_; }

__global__ void __launch_bounds__(256) k_sort(const float* __restrict__ probs,
                                              const float4* __restrict__ boxes,
                                              int* __restrict__ sidx,
                                              float4* __restrict__ sbox,
                                              int* __restrict__ Vc) {
    int c = blockIdx.x;
    int t = threadIdx.x;
    __shared__ u64 a[NPAD];
    __shared__ int vcount;
    if (t == 0) vcount = 0;

    u64 x[8];
    int cnt = 0;
#pragma unroll
    for (int i = 0; i < 8; ++i) {
        int e = 8 * t + i;
        unsigned int u;
        if (e < NROI) {
            float pr = probs[c * NROI + e];
            bool valid = pr > 0.05f;
            cnt += valid ? 1 : 0;
            float key = valid ? pr : -__builtin_inff();
            u = __float_as_uint(key);
        } else {
            u = __float_as_uint(-__builtin_inff());
        }
        u ^= (u >> 31) ? 0xFFFFFFFFu : 0x80000000u;   // order-preserving map
        x[i] = ((u64)(~u) << 32) | (unsigned int)e;   // asc == desc-prob, ties idx asc
    }
    __syncthreads();                 // vcount init visible
    if (cnt) atomicAdd(&vcount, cnt);

    // k=2: up = (i&2)==0
    CSW(0,1,true)  CSW(2,3,false) CSW(4,5,true)  CSW(6,7,false)
    // k=4: up = (i&4)==0
    CSW(0,2,true)  CSW(1,3,true)  CSW(4,6,false) CSW(5,7,false)
    CSW(0,1,true)  CSW(2,3,true)  CSW(4,5,false) CSW(6,7,false)
    // k=8: up = (t&1)==0
    {
        bool up = (t & 1) == 0;
        CSW(0,4,up) CSW(1,5,up) CSW(2,6,up) CSW(3,7,up)
        CSW(0,2,up) CSW(1,3,up) CSW(4,6,up) CSW(5,7,up)
        CSW(0,1,up) CSW(2,3,up) CSW(4,5,up) CSW(6,7,up)
    }
    // k >= 16
    for (unsigned int k = 16; k <= NPAD; k <<= 1) {
        bool up = (((unsigned int)(8 * t)) & k) == 0;
        for (unsigned int j = k >> 1; j >= 8; j >>= 1) {
            if (j >= 512) {                       // cross-wave: LDS
                __syncthreads();
#pragma unroll
                for (int i = 0; i < 8; ++i) a[8 * t + i] = x[i];
                __syncthreads();
                bool lower = ((t & (j >> 3)) == 0);
                bool takeMin = (up == lower);
#pragma unroll
                for (int i = 0; i < 8; ++i) {
                    u64 y = a[(8 * t + i) ^ j];
                    u64 mn = x[i] < y ? x[i] : y;
                    u64 mx = x[i] < y ? y : x[i];
                    x[i] = takeMin ? mn : mx;
                }
            } else {                              // wave-local: shfl_xor
                int lm = (int)(j >> 3);
                bool lower = ((t & lm) == 0);
                bool takeMin = (up == lower);
#pragma unroll
                for (int i = 0; i < 8; ++i) {
                    u64 y = __shfl_xor(x[i], lm, 64);
                    u64 mn = x[i] < y ? x[i] : y;
                    u64 mx = x[i] < y ? y : x[i];
                    x[i] = takeMin ? mn : mx;
                }
            }
        }
        // j = 4,2,1 in registers
        CSW(0,4,up) CSW(1,5,up) CSW(2,6,up) CSW(3,7,up)
        CSW(0,2,up) CSW(1,3,up) CSW(4,6,up) CSW(5,7,up)
        CSW(0,1,up) CSW(2,3,up) CSW(4,5,up) CSW(6,7,up)
    }

#pragma unroll
    for (int i = 0; i < 8; ++i) {
        int e = 8 * t + i;
        u64 p = x[i];
        int orig = (int)(p & 0xFFFFFFFFu);
        sidx[c * NPAD + e] = orig;
        float4 b = (orig < NROI) ? boxes[c * NROI + orig] : make_float4(0, 0, 0, 0);
        sbox[c * NPAD + e] = b;
    }
    __syncthreads();
    if (t == 0) Vc[c] = vcount;
}

// -------- kernel 3: suppression bitmask, lane-per-column + ballot --------
// Wave owns word jb (columns j0..j0+63): column box cached in registers once;
// rows iterate with a uniform broadcast load; __ballot builds the u64 word.
// Covers exactly rows r < min(V, 64*(jb+1)) — the consume-after-write set.
__global__ void __launch_bounds__(256) k_mask(const float4* __restrict__ sbox,
                                              const int* __restrict__ Vc,
                                              u64* __restrict__ mask) {
#pragma clang fp contract(off)
    int c = blockIdx.y;
    int V = Vc[c];
    int jb = blockIdx.x;
    int j0 = jb << 6;
    if (j0 >= V) return;
    int lane = threadIdx.x & 63;
    int wv = threadIdx.x >> 6;
    const float4* sb = sbox + c * NPAD;
    int j = j0 + lane;
    float4 cb = sb[j];
    float areaC = (cb.z - cb.x) * (cb.w - cb.y);
    int rmax = min(V, j0 + 64);
    for (int r = wv; r < rmax; r += 4) {
        float4 rb = sb[r];
        float areaR = (rb.z - rb.x) * (rb.w - rb.y);
        float ty = fmaxf(rb.x, cb.x);
        float tx = fmaxf(rb.y, cb.y);
        float by = fminf(rb.z, cb.z);
        float bx = fminf(rb.w, cb.w);
        float ih = fmaxf(by - ty, 0.0f);
        float iw = fmaxf(bx - tx, 0.0f);
        float inter = ih * iw;
        float denom = ((areaR + areaC) - inter) + 1e-12f;
        float iou = inter / denom;
        u64 bits = __ballot((j > r) && (iou > 0.3f));
        if (lane == 0) mask[((size_t)(c * NPAD) + r) * 32 + jb] = bits;
    }
}

// -------- kernel 4: tiled greedy scan, 1 wave per class --------
__global__ void __launch_bounds__(64, 1) k_scan(const int* __restrict__ sidx,
                                                const int* __restrict__ Vc,
                                                const u64* __restrict__ mask,
                                                int* __restrict__ keepw) {
    int c = blockIdx.x;
    int V = Vc[c];
    if (V <= 0) return;
    int lane = threadIdx.x;
    int w = lane & 31;
    const u64* mbase = mask + (size_t)c * NPAD * 32;
    const int* si = sidx + c * NPAD;

    int ntiles = (V + 63) >> 6;
    u64 remv = 0;
    u64 d = mbase[(size_t)lane * 32 + 0];   // diag block, tile 0

    for (int t = 0; t < ntiles; ++t) {
        u64 dn = 0;
        if (t + 1 < ntiles)
            dn = mbase[(size_t)(64 * (t + 1) + lane) * 32 + (t + 1)];

        // unconditional row-word loads for this tile (independent, batched)
        u64 pf[64];
        const u64* rp = mbase + (size_t)(64 * t) * 32 + w;
#pragma unroll
        for (int j = 0; j < 64; ++j) pf[j] = rp[(size_t)j * 32];

        // register-only greedy resolution on the diagonal block
        u64 rv = __shfl(remv, t);            // word t, uniform
        int rem = V - 64 * t;
        u64 validm = (rem >= 64) ? ~0ULL : ((1ULL << rem) - 1ULL);
        u64 cur = (~rv) & validm;
        u64 kept = 0;
        while (cur) {
            int j = __ffsll((u64)cur) - 1;
            kept |= 1ULL << j;
            cur &= ~__shfl(d, j);
            cur &= ~(1ULL << j);
        }

        // branchless masked accumulate (garbage words are provably masked:
        // word w is consumed at tile w, strictly before any tile > w writes it)
        u64 acc = 0;
#pragma unroll
        for (int j = 0; j < 64; ++j) {
            u64 sel = 0ULL - ((kept >> j) & 1ULL);
            acc |= pf[j] & sel;
        }
        remv |= acc;

        int r = 64 * t + lane;
        if (r < V) keepw[c * NROI + si[r]] = (int)((kept >> lane) & 1ULL);
        d = dn;
    }
}

// -------- kernel 5: final outputs --------
__global__ void k_out(const float4* __restrict__ boxes,
                      const float* __restrict__ probs,
                      const int* __restrict__ keepw,
                      float* __restrict__ out) {
    int t = blockIdx.x * blockDim.x + threadIdx.x;
    if (t >= NFG * NROI) return;
    int c = t / NROI;
    int k = keepw[t];
    float4 b = boxes[t];
    float p = probs[t];
    float* o5 = out + (size_t)t * 5;
    if (k) {
        o5[0] = b.x; o5[1] = b.y; o5[2] = b.z; o5[3] = b.w; o5[4] = p;
    } else {
        o5[0] = 0.0f; o5[1] = 0.0f; o5[2] = 0.0f; o5[3] = 0.0f; o5[4] = 0.0f;
    }
    out[NFG * NROI * 5 + t] = k ? 1.0f : 0.0f;          // keep mask (bool -> 0/1)
    out[NFG * NROI * 6 + t] = (float)c;                 // labels
}

extern "C" void kernel_launch(void* const* d_in, const int* in_sizes, int n_in,
                              void* d_out, int out_size, void* d_ws, size_t ws_size,
                              hipStream_t stream) {
    const float* rois   = (const float*)d_in[0];
    const float* locs   = (const float*)d_in[1];
    const float* scores = (const float*)d_in[2];
    const float* scale  = (const float*)d_in[3];
    float* out = (float*)d_out;

    char* ws = (char*)d_ws;
    float4* boxes = (float4*)(ws + OFF_BOXES);
    float*  probs = (float*)(ws + OFF_PROBS);
    int*    sidx  = (int*)(ws + OFF_SIDX);
    float4* sbox  = (float4*)(ws + OFF_SBOX);
    int*    Vc    = (int*)(ws + OFF_VC);
    int*    keepw = (int*)(ws + OFF_KEEP);
    u64*    mask  = (u64*)(ws + OFF_MASK);

    hipLaunchKernelGGL(k_decode, dim3(32), dim3(64), 0, stream,
                       rois, locs, scores, scale, boxes, probs, keepw);
    hipLaunchKernelGGL(k_sort, dim3(NFG), dim3(256), 0, stream,
                       probs, boxes, sidx, sbox, Vc);
    hipLaunchKernelGGL(k_mask, dim3(32, NFG), dim3(256), 0, stream,
                       sbox, Vc, mask);
    hipLaunchKernelGGL(k_scan, dim3(NFG), dim3(64), 0, stream,
                       sidx, Vc, mask, keepw);
    hipLaunchKernelGGL(k_out, dim3((NFG * NROI + 255) / 256), dim3(256), 0, stream,
                       boxes, probs, keepw, out);
}

// Round 5
// 86.939 us; speedup vs baseline: 2.7928x; 1.1974x over previous
//
#include <hip/hip_runtime.h>
#include <math.h>

#define NROI 2000
#define NCLS 21
#define NFG  20
#define NPAD 2048

// ---- workspace layout (bytes) ----
#define OFF_BOXES   0u          // float4 [NFG*NROI]            640000
#define OFF_PROBS   640000u     // float  [NFG*NROI]            160000
#define OFF_SIDX    800000u     // int    [NFG*NPAD]            163840
#define OFF_SBOX    963840u     // float4 [NFG*NPAD]            655360
#define OFF_VC      1619200u    // int    [NFG] (padded)           128
#define OFF_KEEP    1619328u    // int    [NFG*NROI]            160000
#define OFF_MASK    1779328u    // u64    [NFG*NPAD*32]       10485760
// total ~12.27 MB

typedef unsigned long long u64;

// -------- kernel 1: softmax + box decode + clip; zero keep flags --------
__global__ void k_decode(const float* __restrict__ rois,
                         const float* __restrict__ locs,
                         const float* __restrict__ scores,
                         const float* __restrict__ scale,
                         float4* __restrict__ boxes,
                         float* __restrict__ probs,
                         int* __restrict__ keepw) {
#pragma clang fp contract(off)
    int n = blockIdx.x * blockDim.x + threadIdx.x;
    if (n >= NROI) return;

#pragma unroll
    for (int c = 0; c < NFG; ++c) keepw[c * NROI + n] = 0;

    float s[NCLS];
    float m = -__builtin_inff();
#pragma unroll
    for (int k = 0; k < NCLS; ++k) {
        s[k] = scores[n * NCLS + k];
        m = fmaxf(m, s[k]);
    }
    float sum = 0.0f;
#pragma unroll
    for (int k = 0; k < NCLS; ++k) {
        s[k] = expf(s[k] - m);
        sum += s[k];
    }

    float y1 = rois[n * 4 + 0], x1 = rois[n * 4 + 1];
    float y2 = rois[n * 4 + 2], x2 = rois[n * 4 + 3];
    float h = y2 - y1, w = x2 - x1;
    float cy = y1 + 0.5f * h, cx = x1 + 0.5f * w;
    float sc = scale[0];
    float oh = 600.0f / sc, ow = 800.0f / sc;

#pragma unroll
    for (int c = 1; c < NCLS; ++c) {
        float dy = locs[n * (NCLS * 4) + c * 4 + 0] * 0.1f;
        float dx = locs[n * (NCLS * 4) + c * 4 + 1] * 0.1f;
        float dh = locs[n * (NCLS * 4) + c * 4 + 2] * 0.2f;
        float dw = locs[n * (NCLS * 4) + c * 4 + 3] * 0.2f;
        float ncy = dy * h + cy;
        float ncx = dx * w + cx;
        float nh = expf(dh) * h;
        float nw = expf(dw) * w;
        float b0 = ncy - 0.5f * nh;
        float b1 = ncx - 0.5f * nw;
        float b2 = ncy + 0.5f * nh;
        float b3 = ncx + 0.5f * nw;
        b0 = fminf(fmaxf(b0, 0.0f), oh);
        b1 = fminf(fmaxf(b1, 0.0f), ow);
        b2 = fminf(fmaxf(b2, 0.0f), oh);
        b3 = fminf(fmaxf(b3, 0.0f), ow);
        int o = (c - 1) * NROI + n;
        boxes[o] = make_float4(b0, b1, b2, b3);
        probs[o] = s[c] / sum;
    }
}

// -------- kernel 2: register-resident bitonic sort (256 thr x 8 elems) ----
#define CSW(A,B,UP) { u64 lo_ = x[A] < x[B] ? x[A] : x[B]; \
                      u64 hi_ = x[A] < x[B] ? x[B] : x[A]; \
                      x[A] = (UP) ? lo_ : hi_; x[B] = (UP) ? hi_ : lo_; }

__global__ void __launch_bounds__(256) k_sort(const float* __restrict__ probs,
                                              const float4* __restrict__ boxes,
                                              int* __restrict__ sidx,
                                              float4* __restrict__ sbox,
                                              int* __restrict__ Vc) {
    int c = blockIdx.x;
    int t = threadIdx.x;
    __shared__ u64 a[NPAD];
    __shared__ int vcount;
    if (t == 0) vcount = 0;

    u64 x[8];
    int cnt = 0;
#pragma unroll
    for (int i = 0; i < 8; ++i) {
        int e = 8 * t + i;
        unsigned int u;
        if (e < NROI) {
            float pr = probs[c * NROI + e];
            bool valid = pr > 0.05f;
            cnt += valid ? 1 : 0;
            float key = valid ? pr : -__builtin_inff();
            u = __float_as_uint(key);
        } else {
            u = __float_as_uint(-__builtin_inff());
        }
        u ^= (u >> 31) ? 0xFFFFFFFFu : 0x80000000u;   // order-preserving map
        x[i] = ((u64)(~u) << 32) | (unsigned int)e;   // asc == desc-prob, ties idx asc
    }
    __syncthreads();                 // vcount init visible
    if (cnt) atomicAdd(&vcount, cnt);

    // k=2: up = (i&2)==0
    CSW(0,1,true)  CSW(2,3,false) CSW(4,5,true)  CSW(6,7,false)
    // k=4: up = (i&4)==0
    CSW(0,2,true)  CSW(1,3,true)  CSW(4,6,false) CSW(5,7,false)
    CSW(0,1,true)  CSW(2,3,true)  CSW(4,5,false) CSW(6,7,false)
    // k=8: up = (t&1)==0
    {
        bool up = (t & 1) == 0;
        CSW(0,4,up) CSW(1,5,up) CSW(2,6,up) CSW(3,7,up)
        CSW(0,2,up) CSW(1,3,up) CSW(4,6,up) CSW(5,7,up)
        CSW(0,1,up) CSW(2,3,up) CSW(4,5,up) CSW(6,7,up)
    }
    // k >= 16
    for (unsigned int k = 16; k <= NPAD; k <<= 1) {
        bool up = (((unsigned int)(8 * t)) & k) == 0;
        for (unsigned int j = k >> 1; j >= 8; j >>= 1) {
            if (j >= 512) {                       // cross-wave: LDS
                __syncthreads();
#pragma unroll
                for (int i = 0; i < 8; ++i) a[8 * t + i] = x[i];
                __syncthreads();
                bool lower = ((t & (j >> 3)) == 0);
                bool takeMin = (up == lower);
#pragma unroll
                for (int i = 0; i < 8; ++i) {
                    u64 y = a[(8 * t + i) ^ j];
                    u64 mn = x[i] < y ? x[i] : y;
                    u64 mx = x[i] < y ? y : x[i];
                    x[i] = takeMin ? mn : mx;
                }
            } else {                              // wave-local: shfl_xor
                int lm = (int)(j >> 3);
                bool lower = ((t & lm) == 0);
                bool takeMin = (up == lower);
#pragma unroll
                for (int i = 0; i < 8; ++i) {
                    u64 y = __shfl_xor(x[i], lm, 64);
                    u64 mn = x[i] < y ? x[i] : y;
                    u64 mx = x[i] < y ? y : x[i];
                    x[i] = takeMin ? mn : mx;
                }
            }
        }
        // j = 4,2,1 in registers
        CSW(0,4,up) CSW(1,5,up) CSW(2,6,up) CSW(3,7,up)
        CSW(0,2,up) CSW(1,3,up) CSW(4,6,up) CSW(5,7,up)
        CSW(0,1,up) CSW(2,3,up) CSW(4,5,up) CSW(6,7,up)
    }

#pragma unroll
    for (int i = 0; i < 8; ++i) {
        int e = 8 * t + i;
        u64 p = x[i];
        int orig = (int)(p & 0xFFFFFFFFu);
        sidx[c * NPAD + e] = orig;
        float4 b = (orig < NROI) ? boxes[c * NROI + orig] : make_float4(0, 0, 0, 0);
        sbox[c * NPAD + e] = b;
    }
    __syncthreads();
    if (t == 0) Vc[c] = vcount;
}

// -------- kernel 3: suppression bitmask, LDS-staged + unrolled --------
// Wave owns word jb (columns j0..j0+63). Boxes staged in LDS once
// (coalesced, single vmcnt drain); the row loop then reads via ds_read
// (lgkmcnt) so mask stores (vmcnt) never serialize the loop. Rows
// processed 8-at-a-time per wave (independent ds_reads batched).
// Covers exactly rows r < min(V, j0+64) — the consume-after-write set;
// ballot bits at columns >= V are provably masked by k_scan's validm.
__global__ void __launch_bounds__(512) k_mask(const float4* __restrict__ sbox,
                                              const int* __restrict__ Vc,
                                              u64* __restrict__ mask) {
#pragma clang fp contract(off)
    int c = blockIdx.y;
    int V = Vc[c];
    int jb = blockIdx.x;
    int j0 = jb << 6;
    if (j0 >= V) return;
    int tid = threadIdx.x;
    int lane = tid & 63;
    int wv = tid >> 6;                       // 8 waves
    int rmax = min(V, j0 + 64);
    int smax = j0 + 64;                      // covers rows [0,rmax) and cols [j0,j0+64)

    __shared__ float4 lb[NPAD];
    const float4* sb = sbox + c * NPAD;
    for (int i = tid; i < smax; i += 512) lb[i] = sb[i];
    __syncthreads();

    int j = j0 + lane;
    float4 cb = lb[j];
    float areaC = (cb.z - cb.x) * (cb.w - cb.y);
    u64* mrow = mask + (size_t)(c * NPAD) * 32 + jb;

    for (int r0 = wv * 8; r0 < rmax; r0 += 64) {
#pragma unroll
        for (int k = 0; k < 8; ++k) {
            int r = r0 + k;
            bool act = r < rmax;
            float4 rb = lb[act ? r : 0];
            float areaR = (rb.z - rb.x) * (rb.w - rb.y);
            float ty = fmaxf(rb.x, cb.x);
            float tx = fmaxf(rb.y, cb.y);
            float by = fminf(rb.z, cb.z);
            float bx = fminf(rb.w, cb.w);
            float ih = fmaxf(by - ty, 0.0f);
            float iw = fmaxf(bx - tx, 0.0f);
            float inter = ih * iw;
            float denom = ((areaR + areaC) - inter) + 1e-12f;
            float iou = inter / denom;
            u64 bits = __ballot((j > r) && (iou > 0.3f));
            if (act && lane == 0) mrow[(size_t)r * 32] = bits;
        }
    }
}

// -------- kernel 4: tiled greedy scan, 1 wave per class --------
__global__ void __launch_bounds__(64, 1) k_scan(const int* __restrict__ sidx,
                                                const int* __restrict__ Vc,
                                                const u64* __restrict__ mask,
                                                int* __restrict__ keepw) {
    int c = blockIdx.x;
    int V = Vc[c];
    if (V <= 0) return;
    int lane = threadIdx.x;
    int w = lane & 31;
    const u64* mbase = mask + (size_t)c * NPAD * 32;
    const int* si = sidx + c * NPAD;

    int ntiles = (V + 63) >> 6;
    u64 remv = 0;
    u64 d = mbase[(size_t)lane * 32 + 0];   // diag block, tile 0

    for (int t = 0; t < ntiles; ++t) {
        u64 dn = 0;
        if (t + 1 < ntiles)
            dn = mbase[(size_t)(64 * (t + 1) + lane) * 32 + (t + 1)];

        // unconditional row-word loads for this tile (independent, batched)
        u64 pf[64];
        const u64* rp = mbase + (size_t)(64 * t) * 32 + w;
#pragma unroll
        for (int j = 0; j < 64; ++j) pf[j] = rp[(size_t)j * 32];

        // register-only greedy resolution on the diagonal block
        u64 rv = __shfl(remv, t);            // word t, uniform
        int rem = V - 64 * t;
        u64 validm = (rem >= 64) ? ~0ULL : ((1ULL << rem) - 1ULL);
        u64 cur = (~rv) & validm;
        u64 kept = 0;
        while (cur) {
            int j = __ffsll((u64)cur) - 1;
            kept |= 1ULL << j;
            cur &= ~__shfl(d, j);
            cur &= ~(1ULL << j);
        }

        // branchless masked accumulate (garbage words provably masked:
        // word w is consumed at tile w, strictly before any tile > w writes it)
        u64 acc = 0;
#pragma unroll
        for (int j = 0; j < 64; ++j) {
            u64 sel = 0ULL - ((kept >> j) & 1ULL);
            acc |= pf[j] & sel;
        }
        remv |= acc;

        int r = 64 * t + lane;
        if (r < V) keepw[c * NROI + si[r]] = (int)((kept >> lane) & 1ULL);
        d = dn;
    }
}

// -------- kernel 5: final outputs --------
__global__ void k_out(const float4* __restrict__ boxes,
                      const float* __restrict__ probs,
                      const int* __restrict__ keepw,
                      float* __restrict__ out) {
    int t = blockIdx.x * blockDim.x + threadIdx.x;
    if (t >= NFG * NROI) return;
    int c = t / NROI;
    int k = keepw[t];
    float4 b = boxes[t];
    float p = probs[t];
    float* o5 = out + (size_t)t * 5;
    if (k) {
        o5[0] = b.x; o5[1] = b.y; o5[2] = b.z; o5[3] = b.w; o5[4] = p;
    } else {
        o5[0] = 0.0f; o5[1] = 0.0f; o5[2] = 0.0f; o5[3] = 0.0f; o5[4] = 0.0f;
    }
    out[NFG * NROI * 5 + t] = k ? 1.0f : 0.0f;          // keep mask (bool -> 0/1)
    out[NFG * NROI * 6 + t] = (float)c;                 // labels
}

extern "C" void kernel_launch(void* const* d_in, const int* in_sizes, int n_in,
                              void* d_out, int out_size, void* d_ws, size_t ws_size,
                              hipStream_t stream) {
    const float* rois   = (const float*)d_in[0];
    const float* locs   = (const float*)d_in[1];
    const float* scores = (const float*)d_in[2];
    const float* scale  = (const float*)d_in[3];
    float* out = (float*)d_out;

    char* ws = (char*)d_ws;
    float4* boxes = (float4*)(ws + OFF_BOXES);
    float*  probs = (float*)(ws + OFF_PROBS);
    int*    sidx  = (int*)(ws + OFF_SIDX);
    float4* sbox  = (float4*)(ws + OFF_SBOX);
    int*    Vc    = (int*)(ws + OFF_VC);
    int*    keepw = (int*)(ws + OFF_KEEP);
    u64*    mask  = (u64*)(ws + OFF_MASK);

    hipLaunchKernelGGL(k_decode, dim3(32), dim3(64), 0, stream,
                       rois, locs, scores, scale, boxes, probs, keepw);
    hipLaunchKernelGGL(k_sort, dim3(NFG), dim3(256), 0, stream,
                       probs, boxes, sidx, sbox, Vc);
    hipLaunchKernelGGL(k_mask, dim3(32, NFG), dim3(512), 0, stream,
                       sbox, Vc, mask);
    hipLaunchKernelGGL(k_scan, dim3(NFG), dim3(64), 0, stream,
                       sidx, Vc, mask, keepw);
    hipLaunchKernelGGL(k_out, dim3((NFG * NROI + 255) / 256), dim3(256), 0, stream,
                       boxes, probs, keepw, out);
}